// Round 9
// baseline (1042.865 us; speedup 1.0000x reference)
//
#include <hip/hip_runtime.h>
#include <hip/hip_bf16.h>
#include <stdint.h>

// GNN_758: stacked RelGraphConv x2.  N=50000, E=1.6M, D=128, R=20.
// agg[dst] = sum_r (sum_{e in rel r -> dst} h[src]) @ W[r]; self-loop = rel 20.
// R9: phase 1 = one-hot MFMA aggregation. Per chunk, 32-edge batches:
// A = one-hot routing (dst,rl) built in registers, B = gathered bf16 features
// (16 independent u16 loads/batch/wave), D-accs = S[16dst][5rl][32feat-slice].
// Waves split features; S stored bf16 (union w/ reduction buffer, 33.8 KB LDS
// -> 4 blocks/CU). Wave-uniform control flow, zero LDS atomics, no divergent
// loops. Preprocessing: 12500-bucket (tile,chunk) sort, in-bucket order free.

#define NN 50000
#define NE 1600000
#define DIM 128
#define NREL 20
#define NRELP 21
#define TILE 16
#define NTILE (NN / TILE)          // 3125
#define NBUCKET (NTILE * 4)        // 12500 (tile, chunk)
#define SCAN_EPB 2048
#define NBLK_A ((NBUCKET + SCAN_EPB - 1) / SCAN_EPB)   // 7
#define SB_STR 824                 // u16 per dst row: 6*136 + 8 (16B-aligned, 2-way banks)
#define PACKED_ELEMS (2 * NRELP * 4 * 8 * 64 * 8)   // 688128

typedef __attribute__((ext_vector_type(8))) short short8;
typedef __attribute__((ext_vector_type(4))) float f32x4;

__device__ __forceinline__ unsigned short f32_to_bf16_raw(float f) {
  union { float f; unsigned u; } c; c.f = f;
  unsigned u = c.u;
  return (unsigned short)((u + 0x7fffu + ((u >> 16) & 1u)) >> 16);  // RNE
}

// ---------------- fp32 -> bf16 (x4), nontemporal stores ----------------
__global__ void cvt_bf16_kernel(const float* __restrict__ in,
                                unsigned short* __restrict__ out, int n4) {
  int i = blockIdx.x * 256 + threadIdx.x;
  if (i < n4) {
    float4 f = ((const float4*)in)[i];
    unsigned long long p =
        (unsigned long long)f32_to_bf16_raw(f.x)
      | ((unsigned long long)f32_to_bf16_raw(f.y) << 16)
      | ((unsigned long long)f32_to_bf16_raw(f.z) << 32)
      | ((unsigned long long)f32_to_bf16_raw(f.w) << 48);
    __builtin_nontemporal_store(p, (unsigned long long*)out + i);  // clean -> L3
  }
}

// ---------------- pack W (+loop_w as rel 20) into B-fragment order ----------------
// WP flat: ((((l*21 + r)*4 + ks)*8 + nc)*64 + lane)*8 + j  (verified R0/R1)
__global__ void pack_w_kernel(const float* __restrict__ W,
                              const float* __restrict__ loop_w,
                              unsigned short* __restrict__ WP) {
  int idx = blockIdx.x * 256 + threadIdx.x;
  if (idx >= PACKED_ELEMS) return;
  int j = idx & 7;       int t = idx >> 3;
  int lane = t & 63;     t >>= 6;
  int nc = t & 7;        t >>= 3;
  int ks = t & 3;        t >>= 2;
  int r = t % NRELP;     int l = t / NRELP;
  int k = ks * 32 + (lane >> 4) * 8 + j;
  int n = nc * 16 + (lane & 15);
  float v = (r < NREL) ? W[(((size_t)l * NREL + r) * DIM + k) * DIM + n]
                       : loop_w[((size_t)l * DIM + k) * DIM + n];
  WP[idx] = f32_to_bf16_raw(v);
}

// ---------------- bucket sort by (dst_tile, chunk): hist -> scan -> scatter ----------------
__global__ void hist_kernel(const int* __restrict__ dst, const int* __restrict__ et,
                            unsigned int* __restrict__ cnt, int n) {
  int i = blockIdx.x * 256 + threadIdx.x;
  if (i < n) atomicAdd(&cnt[(dst[i] >> 4) * 4 + et[i] / 5], 1u);
}

__global__ void scanA_kernel(const unsigned int* __restrict__ cnt,
                             unsigned int* __restrict__ ofs,
                             unsigned int* __restrict__ btot) {
  __shared__ unsigned int buf[256];
  int tid = threadIdx.x;
  int base = blockIdx.x * SCAN_EPB + tid * 8;
  unsigned int v[8], p[8], s = 0;
#pragma unroll
  for (int j = 0; j < 8; ++j) {
    v[j] = (base + j < NBUCKET) ? cnt[base + j] : 0u;
    p[j] = s; s += v[j];
  }
  buf[tid] = s;
  __syncthreads();
  for (int d = 1; d < 256; d <<= 1) {
    unsigned int a = (tid >= d) ? buf[tid - d] : 0u;
    __syncthreads();
    buf[tid] += a;
    __syncthreads();
  }
  unsigned int excl = buf[tid] - s;
#pragma unroll
  for (int j = 0; j < 8; ++j)
    if (base + j < NBUCKET) ofs[base + j] = excl + p[j];
  if (tid == 255) btot[blockIdx.x] = buf[255];
}

__global__ void scanB_kernel(unsigned int* __restrict__ btot,
                             unsigned int* __restrict__ ofs) {
  __shared__ unsigned int buf[1024];
  int t = threadIdx.x;
  unsigned int v = (t < NBLK_A) ? btot[t] : 0u;
  buf[t] = v;
  __syncthreads();
  for (int d = 1; d < 1024; d <<= 1) {
    unsigned int a = (t >= d) ? buf[t - d] : 0u;
    __syncthreads();
    buf[t] += a;
    __syncthreads();
  }
  if (t < NBLK_A) btot[t] = buf[t] - v;    // exclusive
  if (t == 1023) ofs[NBUCKET] = buf[1023]; // = NE
}

__global__ void scanC_kernel(const unsigned int* __restrict__ btot,
                             unsigned int* __restrict__ ofs,
                             unsigned int* __restrict__ cursor) {
  int base = blockIdx.x * SCAN_EPB + threadIdx.x * 8;
  unsigned int add = btot[blockIdx.x];
#pragma unroll
  for (int j = 0; j < 8; ++j)
    if (base + j < NBUCKET) {
      unsigned int x = ofs[base + j] + add;
      ofs[base + j] = x;
      cursor[base + j] = x;
    }
}

// payload: src(16b) | rl(3b)<<16 | dst_local(4b)<<19
__global__ void scatter_kernel(const int* __restrict__ src, const int* __restrict__ dst,
                               const int* __restrict__ et,
                               unsigned int* __restrict__ cursor,
                               unsigned int* __restrict__ es, int n) {
  int i = blockIdx.x * 256 + threadIdx.x;
  if (i < n) {
    int d = dst[i], e = et[i];
    unsigned int pos = atomicAdd(&cursor[(d >> 4) * 4 + e / 5], 1u);
    es[pos] = (unsigned int)src[i] | ((unsigned int)(e % 5) << 16)
            | ((unsigned int)(d & 15) << 19);
  }
}

// ---------------- fused RGCN layer ----------------
// 3125 blocks x 256 threads (4 waves). LDS ~33.8 KB -> 4 blocks/CU.
__global__ __launch_bounds__(256, 4) void rgcn_layer_kernel(
    const unsigned short* __restrict__ hb,    // [N,128] bf16
    const unsigned short* __restrict__ WP,    // packed weights
    const float* __restrict__ bias,           // [128] this layer
    int layer,
    const unsigned int* __restrict__ bofs,    // [NBUCKET+1]
    const unsigned int* __restrict__ esg,     // [E] packed, bucket-sorted
    float* __restrict__ outf,                 // fp32 out (layer 1) or null
    unsigned short* __restrict__ outb)        // bf16 out (layer 0) or null
{
  __shared__ __align__(16) unsigned char smem[33792];  // Sb (26368 B) / red (33792 B)
  __shared__ unsigned int bofs_l[5];
  unsigned short (*Sb)[SB_STR] = (unsigned short (*)[SB_STR])smem;
  float* red = (float*)smem;

  const int tid  = threadIdx.x;
  const int lane = tid & 63;
  const int w    = tid >> 6;        // wave = feature-slice owner [32w, 32w+32)
  const int quad = lane >> 4;
  const int m    = lane & 15;
  const int dst_base = blockIdx.x * TILE;

  if (tid < 5) bofs_l[tid] = bofs[blockIdx.x * 4 + tid];
  __syncthreads();

  f32x4 acc2[8];
#pragma unroll
  for (int nc = 0; nc < 8; ++nc) acc2[nc] = (f32x4){0.f, 0.f, 0.f, 0.f};

  const short one_bf = (short)0x3F80;   // bf16 1.0

  for (int c = 0; c < 4; ++c) {
    const int rc = (c == 3) ? 6 : 5;
    const int ebeg = (int)bofs_l[c];
    const int cnt  = (int)bofs_l[c + 1] - ebeg;

    // ---- phase 1: one-hot MFMA aggregation over 32-edge batches ----
    f32x4 agg[5][2];
#pragma unroll
    for (int rl = 0; rl < 5; ++rl) {
      agg[rl][0] = (f32x4){0.f, 0.f, 0.f, 0.f};
      agg[rl][1] = (f32x4){0.f, 0.f, 0.f, 0.f};
    }

    for (int b0 = 0; b0 < cnt; b0 += 32) {
      const int kbase = b0 + quad * 8;
      unsigned int ew[8];
#pragma unroll
      for (int j = 0; j < 8; ++j) {
        int k = kbase + j; if (k >= cnt) k = cnt - 1;   // clamp (valid addr)
        ew[j] = esg[ebeg + k];
      }
      short8 bf0, bf1;                 // B-frags: my 2 feature tiles of 8 edges
#pragma unroll
      for (int j = 0; j < 8; ++j) {
        const unsigned short* rp = hb + (size_t)(ew[j] & 0xffffu) * DIM + w * 32 + m;
        bf0[j] = (short)rp[0];
        bf1[j] = (short)rp[16];
      }
      int hj[8];                       // target id (dst*8 | rl), -1 if padded
      const int kv = cnt - kbase;
#pragma unroll
      for (int j = 0; j < 8; ++j)
        hj[j] = (j < kv) ? (int)((ew[j] >> 16) & 0x7fu) : -1;
#pragma unroll
      for (int rl = 0; rl < 5; ++rl) {
        const int key = (m << 3) | rl;
        short8 a;
#pragma unroll
        for (int j = 0; j < 8; ++j) a[j] = (hj[j] == key) ? one_bf : (short)0;
        agg[rl][0] = __builtin_amdgcn_mfma_f32_16x16x32_bf16(a, bf0, agg[rl][0], 0, 0, 0);
        agg[rl][1] = __builtin_amdgcn_mfma_f32_16x16x32_bf16(a, bf1, agg[rl][1], 0, 0, 0);
      }
    }

    // agg -> Sb (bf16). D layout: row(dst)=quad*4+i, col(feat)=m  [m89-verified]
#pragma unroll
    for (int rl = 0; rl < 5; ++rl)
#pragma unroll
      for (int nc2 = 0; nc2 < 2; ++nc2)
#pragma unroll
        for (int i = 0; i < 4; ++i)
          Sb[quad * 4 + i][rl * 136 + w * 32 + nc2 * 16 + m] =
              f32_to_bf16_raw(agg[rl][nc2][i]);
    if (c == 3) {                      // self-loop -> slot 5, direct bf16 copy
      const int g = w * 4 + quad;
      short8 hv = *(const short8*)(hb + (size_t)(dst_base + g) * DIM + m * 8);
      *(short8*)&Sb[g][5 * 136 + m * 8] = hv;
    }
    __syncthreads();

    // ---- phase 2: K-split MFMA. wave w owns k=[32w,32w+32); A = ds_read_b128 ----
    for (int rl = 0; rl < rc; ++rl) {
      const int r = c * 5 + rl;        // c==3, rl==5 -> r=20 (self-loop)
      short8 a = *(const short8*)&Sb[m][rl * 136 + w * 32 + quad * 8];
      const unsigned short* bp =
          WP + ((((size_t)(layer * NRELP + r) * 4 + w) * 8) * 64 + lane) * 8;
#pragma unroll
      for (int nc = 0; nc < 8; ++nc) {
        short8 b = *(const short8*)(bp + (size_t)nc * 64 * 8);
        acc2[nc] = __builtin_amdgcn_mfma_f32_16x16x32_bf16(a, b, acc2[nc], 0, 0, 0);
      }
    }
    __syncthreads();
  }

  // cross-wave K-reduction (red overlays Sb; Sb dead). red[w][row16][132]
#pragma unroll
  for (int nc = 0; nc < 8; ++nc)
#pragma unroll
    for (int i = 0; i < 4; ++i)
      red[w * 2112 + (quad * 4 + i) * 132 + nc * 16 + m] = acc2[nc][i];
  __syncthreads();

  {
    int row = tid >> 4, cb = (tid & 15) * 8;
    float4 b0 = *(const float4*)(bias + cb);
    float4 b1 = *(const float4*)(bias + cb + 4);
    float o[8];
#pragma unroll
    for (int j = 0; j < 8; ++j) {
      int col = cb + j;
      o[j] = red[0 * 2112 + row * 132 + col] + red[1 * 2112 + row * 132 + col]
           + red[2 * 2112 + row * 132 + col] + red[3 * 2112 + row * 132 + col];
    }
    o[0] += b0.x; o[1] += b0.y; o[2] += b0.z; o[3] += b0.w;
    o[4] += b1.x; o[5] += b1.y; o[6] += b1.z; o[7] += b1.w;
    if (outb) {
      short8 p;
#pragma unroll
      for (int j = 0; j < 8; ++j) p[j] = (short)f32_to_bf16_raw(o[j]);
      __builtin_nontemporal_store(p, (short8*)(outb + (size_t)(dst_base + row) * DIM + cb));
    } else {
      float* op = outf + (size_t)(dst_base + row) * DIM + cb;
      *(float4*)op       = (float4){o[0], o[1], o[2], o[3]};
      *(float4*)(op + 4) = (float4){o[4], o[5], o[6], o[7]};
    }
  }
}

// ---------------- launch ----------------
extern "C" void kernel_launch(void* const* d_in, const int* in_sizes, int n_in,
                              void* d_out, int out_size, void* d_ws, size_t ws_size,
                              hipStream_t stream) {
  const float* h0     = (const float*)d_in[0];
  const float* W      = (const float*)d_in[1];
  const float* loop_w = (const float*)d_in[2];
  const float* bias   = (const float*)d_in[3];
  const int* esrc     = (const int*)d_in[4];
  const int* edst     = (const int*)d_in[5];
  const int* etyp     = (const int*)d_in[6];
  float* out = (float*)d_out;

  char* ws = (char*)d_ws;
  size_t off = 0;
  auto alloc = [&](size_t bytes) -> void* {
    void* p = ws + off;
    off = (off + bytes + 255) & ~(size_t)255;
    return p;
  };
  unsigned short* hb0  = (unsigned short*)alloc((size_t)NN * DIM * 2);     // 12.8 MB
  unsigned short* hb1  = (unsigned short*)alloc((size_t)NN * DIM * 2);     // 12.8 MB
  unsigned short* WP   = (unsigned short*)alloc((size_t)PACKED_ELEMS * 2);
  unsigned int*   cnt  = (unsigned int*)alloc((size_t)NBUCKET * 4);
  unsigned int*   ofs  = (unsigned int*)alloc((size_t)(NBUCKET + 1) * 4);
  unsigned int*   cur  = (unsigned int*)alloc((size_t)NBUCKET * 4);
  unsigned int*   btot = (unsigned int*)alloc((size_t)NBLK_A * 4);
  unsigned int*   es   = (unsigned int*)alloc((size_t)NE * 4);             // 6.4 MB

  (void)hipMemsetAsync(cnt, 0, (size_t)NBUCKET * 4, stream);
  hist_kernel<<<NE / 256, 256, 0, stream>>>(edst, etyp, cnt, NE);
  scanA_kernel<<<NBLK_A, 256, 0, stream>>>(cnt, ofs, btot);
  scanB_kernel<<<1, 1024, 0, stream>>>(btot, ofs);
  scanC_kernel<<<NBLK_A, 256, 0, stream>>>(btot, ofs, cur);
  scatter_kernel<<<NE / 256, 256, 0, stream>>>(esrc, edst, etyp, cur, es, NE);

  pack_w_kernel<<<(PACKED_ELEMS + 255) / 256, 256, 0, stream>>>(W, loop_w, WP);
  cvt_bf16_kernel<<<(NN * DIM / 4 + 255) / 256, 256, 0, stream>>>(h0, hb0, NN * DIM / 4);

  rgcn_layer_kernel<<<NTILE, 256, 0, stream>>>(hb0, WP, bias, 0, ofs, es,
                                               nullptr, hb1);
  rgcn_layer_kernel<<<NTILE, 256, 0, stream>>>(hb1, WP, bias + DIM, 1, ofs, es,
                                               out, nullptr);
}